// Round 9
// baseline (1670.754 us; speedup 1.0000x reference)
//
#include <hip/hip_runtime.h>

// Seq2Seq LSTM (B=1024, T_IN=168, F_IN=8, H=256, T_OUT=96) on gfx950.
// Round 9: BARRIER-FREE flag-synced design. r3/r7/r8 analysis showed step
// time = 3-4x sum of pipe busy-times -> 8-wave lockstep convoy between
// __syncthreads. Replace the block barrier with per-wave progress flags in
// LDS: A-frag kt k depends only on wave k's h-slice, so a wave checks
// flg[0..3] >= it before kt0-3 and flg[4..7] >= it before kt4-7, and posts
// flg[wv] = it+1 (threadfence_block release) after writing its slice.
// Waves slip up to 1 step; A is double-buffered (safe at skew<=1: a wave
// writes buf[(it+1)&1] only after observing all flags >= it, which implies
// everyone finished reading that buffer's previous content).
//   weights: kt0-3 + kt8 VGPR (40 frags, r3 budget) | kt4,kt5 streamed
//            (one reused 8-frag reg set) | kt6,7 LDS (128 KB)
//   x: per-wave direct L2 loads (no xs staging, no cross-wave dep)
//   decoder: rank-1 x-fold (r8), partial[] dbuf, full-join via both ckpts
// 64 blocks x 512 threads; wave wv owns h-units [wv*32, +32).

typedef _Float16 f16x8 __attribute__((ext_vector_type(8)));
typedef float f32x4 __attribute__((ext_vector_type(4)));

#define WPW  36864
#define NENC 168
#define NDEC 96

__device__ __forceinline__ float sigm(float x) {
    float e = __builtin_amdgcn_exp2f(-1.4426950408889634f * x);
    return __builtin_amdgcn_rcpf(1.0f + e);
}
__device__ __forceinline__ float tanh_f(float x) {
    float e = __builtin_amdgcn_exp2f(-2.8853900817779268f * x);
    return 2.0f * __builtin_amdgcn_rcpf(1.0f + e) - 1.0f;
}
__device__ __forceinline__ f32x4 mfma(f16x8 a, f16x8 b, f32x4 c) {
    return __builtin_amdgcn_mfma_f32_16x16x32_f16(a, b, c, 0, 0, 0);
}
__device__ __forceinline__ void mfma8(f32x4 acc[8], f16x8 a, const f16x8 b[8]) {
#pragma unroll
    for (int nt = 0; nt < 8; ++nt) acc[nt] = mfma(a, b[nt], acc[nt]);
}

// ---------- setup kernels (unchanged) ----------

__global__ void k_convert_x(const float* __restrict__ in, _Float16* __restrict__ xf16) {
    int idx = blockIdx.x * 256 + threadIdx.x;     // (t*1024+b)*8+f
    if (idx >= 168 * 1024 * 8) return;
    int f = idx & 7;
    int b = (idx >> 3) & 1023;
    int t = idx >> 13;
    xf16[idx] = (_Float16)in[(b * 168 + t) * 8 + f];
}

__global__ void k_pack_w(const float* __restrict__ Whh, const float* __restrict__ Wih,
                         int IN, _Float16* __restrict__ Wp) {
    int idx = blockIdx.x * 256 + threadIdx.x;
    if (idx >= 294912) return;
    int j    = idx & 7;
    int lane = (idx >> 3) & 63;
    int nt   = (idx >> 9) & 7;
    int kt   = (idx >> 12) % 9;
    int wv   = idx / 36864;
    int n = (nt >> 1) * 256 + wv * 32 + (nt & 1) * 16 + (lane & 15);
    int k = kt * 32 + (lane >> 4) * 8 + j;
    float v = 0.0f;
    if (k < 256)            v = Whh[n * 256 + k];
    else if (k - 256 < IN)  v = Wih[n * IN + (k - 256)];
    Wp[idx] = (_Float16)v;
}

// ---------- main persistent kernel ----------

__global__ __launch_bounds__(512, 2) void lstm9(
    const float* __restrict__ in0,
    const _Float16* __restrict__ xf16,
    const _Float16* __restrict__ WpE,
    const _Float16* __restrict__ WpD,
    const float* __restrict__ bihE, const float* __restrict__ bhhE,
    const float* __restrict__ bihD, const float* __restrict__ bhhD,
    const float* __restrict__ dWih,
    const float* __restrict__ fcW, const float* __restrict__ fcb,
    float* __restrict__ out) {

    __shared__ f16x8 Blds[8][16][64];       // 128 KB: kt6,7 (wave-local slices)
    __shared__ _Float16 A[2][16 * 256];     //  16 KB: h tile, dbuf, swizzled
    __shared__ f32x4 partial[2][16][2];     //   1 KB: decoder fc partials, dbuf
    __shared__ unsigned flg[8];             // per-wave completed-step counters

    const int tid  = threadIdx.x;
    const int lane = tid & 63;
    const int wv   = tid >> 6;
    const int l15  = lane & 15;
    const int lg   = lane >> 4;
    const int b0   = blockIdx.x * 16;

    const _Float16* wpe = WpE + wv * WPW;
    const _Float16* wpd = WpD + wv * WPW;

    // weights: kt0-3 + kt8 -> VGPR (40 frags); kt6,7 -> LDS
    f16x8 wr[4][8], wk8[8];
#pragma unroll
    for (int kt = 0; kt < 4; ++kt)
#pragma unroll
        for (int nt = 0; nt < 8; ++nt)
            wr[kt][nt] = *(const f16x8*)(wpe + (size_t)(kt * 8 + nt) * 512 + lane * 8);
#pragma unroll
    for (int nt = 0; nt < 8; ++nt)
        wk8[nt] = *(const f16x8*)(wpe + (size_t)(8 * 8 + nt) * 512 + lane * 8);
#pragma unroll
    for (int kt = 6; kt < 8; ++kt)
#pragma unroll
        for (int nt = 0; nt < 8; ++nt)
            Blds[wv][(kt - 6) * 8 + nt][lane] = *(const f16x8*)(wpe + (size_t)(kt * 8 + nt) * 512 + lane * 8);

    float bia[8];
#pragma unroll
    for (int nt = 0; nt < 8; ++nt) {
        int n = (nt >> 1) * 256 + wv * 32 + (nt & 1) * 16 + l15;
        bia[nt] = bihE[n] + bhhE[n];
    }
    const float fcw0 = fcW[wv * 32 + l15];
    const float fcw1 = fcW[wv * 32 + 16 + l15];
    const float fcbv = fcb[0];

    // swizzled A-frag read offsets (kt 0..7), byte offsets within one 8KB buffer
    int aaddr[8];
#pragma unroll
    for (int kt = 0; kt < 8; ++kt)
        aaddr[kt] = l15 * 512 + kt * 64 + ((lg * 16) ^ ((l15 & 3) << 4));

    // zero A[0] (h0 = 0), zero flags
    for (int i = tid; i < 16 * 256; i += 512) A[0][i] = (_Float16)0.0f;
    if (tid < 8) flg[tid] = 0u;

    float c_st[2][4] = {{0.f,0.f,0.f,0.f},{0.f,0.f,0.f,0.f}};

    __syncthreads();    // the ONLY barrier in the kernel (init visibility)

#define WAIT4(BASE, TGT)                                                              \
    for (;;) {                                                                        \
        unsigned f0 = __hip_atomic_load(&flg[(BASE)+0], __ATOMIC_RELAXED, __HIP_MEMORY_SCOPE_WORKGROUP); \
        unsigned f1 = __hip_atomic_load(&flg[(BASE)+1], __ATOMIC_RELAXED, __HIP_MEMORY_SCOPE_WORKGROUP); \
        unsigned f2 = __hip_atomic_load(&flg[(BASE)+2], __ATOMIC_RELAXED, __HIP_MEMORY_SCOPE_WORKGROUP); \
        unsigned f3 = __hip_atomic_load(&flg[(BASE)+3], __ATOMIC_RELAXED, __HIP_MEMORY_SCOPE_WORKGROUP); \
        if (f0 >= (TGT) && f1 >= (TGT) && f2 >= (TGT) && f3 >= (TGT)) break;          \
        __builtin_amdgcn_s_sleep(1);                                                  \
    }                                                                                 \
    __threadfence_block();

#define POST_FLAG(VAL)                                                                \
    __threadfence_block();                                                            \
    if (lane == 0)                                                                    \
        __hip_atomic_store(&flg[wv], (unsigned)(VAL), __ATOMIC_RELAXED, __HIP_MEMORY_SCOPE_WORKGROUP);

    // ===================== encoder: 168 steps, no barriers =====================
#pragma unroll 1
    for (int it = 0; it < NENC; ++it) {
        const int rb = it & 1, wbuf = rb ^ 1;
        const char* ab = (const char*)&A[0][0] + rb * 8192;
        char*       aw = (char*)&A[0][0] + wbuf * 8192;
        const unsigned tgt = (unsigned)it;

        // flag-independent loads first: kt4 stream + this step's x
        f16x8 s[8];
#pragma unroll
        for (int nt = 0; nt < 8; ++nt)
            s[nt] = *(const f16x8*)(wpe + (size_t)(4 * 8 + nt) * 512 + lane * 8);
        f16x8 xa = *(const f16x8*)(xf16 + ((size_t)it * 1024 + b0 + l15) * 8);

        f32x4 acc[8];
#pragma unroll
        for (int nt = 0; nt < 8; ++nt) { f32x4 v = {bia[nt], bia[nt], bia[nt], bia[nt]}; acc[nt] = v; }

        WAIT4(0, tgt)                      // slices 0-3 ready
#pragma unroll
        for (int kt = 0; kt < 4; ++kt) {
            f16x8 a = *(const f16x8*)(ab + aaddr[kt]);
            mfma8(acc, a, wr[kt]);
        }
        WAIT4(4, tgt)                      // slices 4-7 ready
        {
            f16x8 a = *(const f16x8*)(ab + aaddr[4]);
            mfma8(acc, a, s);              // kt4 (streamed)
        }
#pragma unroll
        for (int nt = 0; nt < 8; ++nt)     // kt5 stream into the same regs
            s[nt] = *(const f16x8*)(wpe + (size_t)(5 * 8 + nt) * 512 + lane * 8);
        {
            f16x8 a = *(const f16x8*)(ab + aaddr[6]);
#pragma unroll
            for (int nt = 0; nt < 8; ++nt) acc[nt] = mfma(a, Blds[wv][nt][lane], acc[nt]);
        }
        {
            f16x8 a = *(const f16x8*)(ab + aaddr[5]);
            mfma8(acc, a, s);              // kt5 (streamed)
        }
        {
            f16x8 a = *(const f16x8*)(ab + aaddr[7]);
#pragma unroll
            for (int nt = 0; nt < 8; ++nt) acc[nt] = mfma(a, Blds[wv][8 + nt][lane], acc[nt]);
        }
        mfma8(acc, xa, wk8);               // kt8 (B-frags are 0 beyond features)

        // activation + h write (swizzled) into the other buffer
#pragma unroll
        for (int half = 0; half < 2; ++half) {
#pragma unroll
            for (int r = 0; r < 4; ++r) {
                float iv = acc[0 + half][r];
                float fv = acc[2 + half][r];
                float gv = acc[4 + half][r];
                float ov = acc[6 + half][r];
                float cn = sigm(fv) * c_st[half][r] + sigm(iv) * tanh_f(gv);
                c_st[half][r] = cn;
                float hn = sigm(ov) * tanh_f(cn);
                int row  = lg * 4 + r;
                int colb = (wv * 32 + half * 16 + l15) * 2;
                *(_Float16*)(aw + row * 512 + (colb ^ ((r & 3) << 4))) = (_Float16)hn;
            }
        }
        POST_FLAG(it + 1)
    }

    // ---------- phase switch (fully wave-local; flags handle cross-wave deps) ----------
#pragma unroll
    for (int kt = 0; kt < 4; ++kt)
#pragma unroll
        for (int nt = 0; nt < 8; ++nt)
            wr[kt][nt] = *(const f16x8*)(wpd + (size_t)(kt * 8 + nt) * 512 + lane * 8);
#pragma unroll
    for (int kt = 6; kt < 8; ++kt)
#pragma unroll
        for (int nt = 0; nt < 8; ++nt)
            Blds[wv][(kt - 6) * 8 + nt][lane] = *(const f16x8*)(wpd + (size_t)(kt * 8 + nt) * 512 + lane * 8);
    float wih_s[8];
#pragma unroll
    for (int nt = 0; nt < 8; ++nt) {
        int n = (nt >> 1) * 256 + wv * 32 + (nt & 1) * 16 + l15;
        bia[nt]   = bihD[n] + bhhD[n];
        wih_s[nt] = dWih[n];
    }
    float pred[4];
#pragma unroll
    for (int r = 0; r < 4; ++r)
        pred[r] = in0[((size_t)(b0 + lg * 4 + r) * 168 + 167) * 8 + 0];

    // ===================== decoder: 96 steps, no barriers =====================
#pragma unroll 1
    for (int sd = 0; sd < NDEC; ++sd) {
        const int it = NENC + sd;
        const int rb = it & 1, wbuf = rb ^ 1;
        const char* ab = (const char*)&A[0][0] + rb * 8192;
        char*       aw = (char*)&A[0][0] + wbuf * 8192;
        const unsigned tgt = (unsigned)it;

        f16x8 s[8];
#pragma unroll
        for (int nt = 0; nt < 8; ++nt)
            s[nt] = *(const f16x8*)(wpd + (size_t)(4 * 8 + nt) * 512 + lane * 8);

        WAIT4(0, tgt)
        WAIT4(4, tgt)                      // full join: pred needs all partials

        if (sd > 0) {
#pragma unroll
            for (int r = 0; r < 4; ++r) {
                const int row = lg * 4 + r;
                f32x4 pa = partial[rb][row][0];
                f32x4 pb = partial[rb][row][1];
                pred[r] = fcbv + (((pa[0] + pa[1]) + (pa[2] + pa[3]))
                                + ((pb[0] + pb[1]) + (pb[2] + pb[3])));
                if (wv == 0 && l15 == 0)
                    out[(size_t)(b0 + row) * 96 + (sd - 1)] = pred[r];
            }
        }

        f32x4 acc[8];
#pragma unroll
        for (int nt = 0; nt < 8; ++nt) {
            f32x4 v;
#pragma unroll
            for (int r = 0; r < 4; ++r) v[r] = __builtin_fmaf(wih_s[nt], pred[r], bia[nt]);
            acc[nt] = v;
        }

#pragma unroll
        for (int kt = 0; kt < 4; ++kt) {
            f16x8 a = *(const f16x8*)(ab + aaddr[kt]);
            mfma8(acc, a, wr[kt]);
        }
        {
            f16x8 a = *(const f16x8*)(ab + aaddr[4]);
            mfma8(acc, a, s);
        }
#pragma unroll
        for (int nt = 0; nt < 8; ++nt)
            s[nt] = *(const f16x8*)(wpd + (size_t)(5 * 8 + nt) * 512 + lane * 8);
        {
            f16x8 a = *(const f16x8*)(ab + aaddr[6]);
#pragma unroll
            for (int nt = 0; nt < 8; ++nt) acc[nt] = mfma(a, Blds[wv][nt][lane], acc[nt]);
        }
        {
            f16x8 a = *(const f16x8*)(ab + aaddr[5]);
            mfma8(acc, a, s);
        }
        {
            f16x8 a = *(const f16x8*)(ab + aaddr[7]);
#pragma unroll
            for (int nt = 0; nt < 8; ++nt) acc[nt] = mfma(a, Blds[wv][8 + nt][lane], acc[nt]);
        }

        float hnv[2][4];
#pragma unroll
        for (int half = 0; half < 2; ++half) {
#pragma unroll
            for (int r = 0; r < 4; ++r) {
                float iv = acc[0 + half][r];
                float fv = acc[2 + half][r];
                float gv = acc[4 + half][r];
                float ov = acc[6 + half][r];
                float cn = sigm(fv) * c_st[half][r] + sigm(iv) * tanh_f(gv);
                c_st[half][r] = cn;
                float hn = sigm(ov) * tanh_f(cn);
                hnv[half][r] = hn;
                int row  = lg * 4 + r;
                int colb = (wv * 32 + half * 16 + l15) * 2;
                *(_Float16*)(aw + row * 512 + (colb ^ ((r & 3) << 4))) = (_Float16)hn;
            }
        }
#pragma unroll
        for (int r = 0; r < 4; ++r) {
            float pv = hnv[0][r] * fcw0 + hnv[1][r] * fcw1;
            pv += __shfl_xor(pv, 1);
            pv += __shfl_xor(pv, 2);
            pv += __shfl_xor(pv, 4);
            pv += __shfl_xor(pv, 8);
            if (l15 == 0)
                ((float*)&partial[wbuf][lg * 4 + r][0])[wv] = pv;
        }
        POST_FLAG(it + 1)
    }

    // tail: last prediction (it=263 wrote partial[0]; need all waves done)
    if (wv == 0) {
        WAIT4(0, (unsigned)(NENC + NDEC))
        WAIT4(4, (unsigned)(NENC + NDEC))
        if (l15 == 0) {
#pragma unroll
            for (int r = 0; r < 4; ++r) {
                const int row = lg * 4 + r;
                f32x4 pa = partial[0][row][0];
                f32x4 pb = partial[0][row][1];
                float pr = fcbv + (((pa[0] + pa[1]) + (pa[2] + pa[3]))
                                 + ((pb[0] + pb[1]) + (pb[2] + pb[3])));
                out[(size_t)(b0 + row) * 96 + 95] = pr;
            }
        }
    }
#undef WAIT4
#undef POST_FLAG
}

// ---------- launch ----------

extern "C" void kernel_launch(void* const* d_in, const int* in_sizes, int n_in,
                              void* d_out, int out_size, void* d_ws, size_t ws_size,
                              hipStream_t stream) {
    const float* inputs  = (const float*)d_in[0];
    const float* enc_Wih = (const float*)d_in[1];
    const float* enc_Whh = (const float*)d_in[2];
    const float* enc_bih = (const float*)d_in[3];
    const float* enc_bhh = (const float*)d_in[4];
    const float* dec_Wih = (const float*)d_in[5];
    const float* dec_Whh = (const float*)d_in[6];
    const float* dec_bih = (const float*)d_in[7];
    const float* dec_bhh = (const float*)d_in[8];
    const float* fc_W    = (const float*)d_in[9];
    const float* fc_b    = (const float*)d_in[10];

    char* ws = (char*)d_ws;
    _Float16* xf16 = (_Float16*)(ws);
    _Float16* WpE  = (_Float16*)(ws + 2752512);
    _Float16* WpD  = (_Float16*)(ws + 2752512 + 589824);

    k_convert_x<<<dim3(5376), dim3(256), 0, stream>>>(inputs, xf16);
    k_pack_w<<<dim3(1152), dim3(256), 0, stream>>>(enc_Whh, enc_Wih, 8, WpE);
    k_pack_w<<<dim3(1152), dim3(256), 0, stream>>>(dec_Whh, dec_Wih, 1, WpD);

    lstm9<<<dim3(64), dim3(512), 0, stream>>>(
        inputs, xf16, WpE, WpD, enc_bih, enc_bhh, dec_bih, dec_bhh,
        dec_Wih, fc_W, fc_b, (float*)d_out);
}